// Round 17
// baseline (124.682 us; speedup 1.0000x reference)
//
#include <hip/hip_runtime.h>

typedef unsigned short u16;
typedef unsigned int u32;
typedef __attribute__((ext_vector_type(4))) float f32x4;
typedef __attribute__((ext_vector_type(8))) short bf16x8;
typedef __attribute__((address_space(1))) const u32* gp1_t;
typedef __attribute__((address_space(3))) u32* lp3_t;

#define H 768
#define V 32000
#define MROWS 2048   // B*C*32 = 4*16*32
#define NT 24        // 768 / 32
#define NCONV 6000   // conv blocks: 6000 * 1024 float4 = V*H/4

__device__ __forceinline__ u16 f2bf(float f) {
  u32 x = __float_as_uint(f);
  x += 0x7fffu + ((x >> 16) & 1u);   // round-to-nearest-even
  return (u16)(x >> 16);
}

// Deterministic compaction: active rows sorted by (b,c,t). pre[j] = exclusive prefix
// over the 64 chunks' active counts; pre[64] = cnt. Wave-parallel scan on wave 0.
__device__ __forceinline__ int build_prefix(const int* __restrict__ split,
                                            const int* __restrict__ nch,
                                            int* pre, int tid) {
  if (tid < 64) {
    int b = tid >> 4, c = tid & 15;
    int sz = (c < nch[b]) ? split[tid] : 0;
    sz = sz < 32 ? sz : 32;
    int incl = sz;
    #pragma unroll
    for (int d = 1; d < 64; d <<= 1) {
      int up = __shfl_up(incl, d, 64);
      if (tid >= d) incl += up;
    }
    pre[tid] = incl - sz;              // exclusive prefix
    if (tid == 63) pre[64] = incl;     // total
  }
  __syncthreads();
  return pre[64];
}

__device__ __forceinline__ int slot2row(const int* pre, int s) {
  int lo = 0, hi = 63;
  while (lo < hi) { int mid = (lo + hi + 1) >> 1; if (pre[mid] <= s) lo = mid; else hi = mid - 1; }
  return lo * 32 + (s - pre[lo]);   // (b*16+c)*32 + t
}

// ---- kernel 1: {zfill inactive out rows} + {wemb f32->bf16} + {W_dec^T} + {E gather} ----
// All four jobs are mutually independent -> the 200 MB zero stream and the 147 MB conv
// stream overlap with the tiny prep work, filling the machine before the GEMM chain.
// blocks: [0,2048) zfill; [2048,8048) conv; [8048,8192) wdecT; [8192,8192+2048) egather.
__global__ void prepZ_kernel(const float* __restrict__ wemb, u16* __restrict__ wemb_bf,
                             const float* __restrict__ wdec, u16* __restrict__ wdecT,
                             const int* __restrict__ tok_ids,
                             const int* __restrict__ split, const int* __restrict__ nch,
                             u16* __restrict__ e_bf, float* __restrict__ out) {
  if (blockIdx.x < MROWS) {
    int row = blockIdx.x;
    int b = row >> 9, c = (row >> 5) & 15, t = row & 31;
    if (c < nch[b] && t < split[b * 16 + c]) return;   // active -> gemm writes it
    const f32x4 z = {0.f, 0.f, 0.f, 0.f};
    f32x4* p = reinterpret_cast<f32x4*>(out + (size_t)row * V);
    for (int i = threadIdx.x; i < V / 4; i += 256)
      __builtin_nontemporal_store(z, p + i);
  } else if (blockIdx.x < MROWS + NCONV) {
    int base = (blockIdx.x - MROWS) * 1024;      // float4 index
    const float4* in4 = reinterpret_cast<const float4*>(wemb);
    ushort4* out4 = reinterpret_cast<ushort4*>(wemb_bf);
    #pragma unroll
    for (int j = 0; j < 4; ++j) {
      int i = base + j * 256 + threadIdx.x;
      float4 v = in4[i];
      ushort4 o;
      o.x = f2bf(v.x); o.y = f2bf(v.y); o.z = f2bf(v.z); o.w = f2bf(v.w);
      out4[i] = o;
    }
  } else if (blockIdx.x < MROWS + NCONV + 144) {
    __shared__ float tile[64][65];
    int b = blockIdx.x - MROWS - NCONV;
    int hb = (b / 12) * 64, jb = (b % 12) * 64;
    #pragma unroll
    for (int rr = 0; rr < 64; rr += 16) {
      int r = rr + (threadIdx.x >> 4);
      int c = (threadIdx.x & 15) * 4;
      float4 v = *reinterpret_cast<const float4*>(&wdec[(size_t)(hb + r) * H + jb + c]);
      tile[r][c] = v.x; tile[r][c + 1] = v.y; tile[r][c + 2] = v.z; tile[r][c + 3] = v.w;
    }
    __syncthreads();
    #pragma unroll
    for (int rr = 0; rr < 64; rr += 16) {
      int r = rr + (threadIdx.x >> 4);      // j
      int c = (threadIdx.x & 15) * 4;       // h group
      ushort4 o;
      o.x = f2bf(tile[c][r]); o.y = f2bf(tile[c + 1][r]);
      o.z = f2bf(tile[c + 2][r]); o.w = f2bf(tile[c + 3][r]);
      *reinterpret_cast<ushort4*>(&wdecT[(size_t)(jb + r) * H + hb + c]) = o;
    }
  } else {
    __shared__ int pre[65];
    int tid = threadIdx.x;
    int cnt = build_prefix(split, nch, pre, tid);
    int s = blockIdx.x - MROWS - NCONV - 144;
    int c4 = tid * 4;
    if (c4 >= H) return;
    ushort4 o = {0, 0, 0, 0};
    if (s < cnt) {
      int row = slot2row(pre, s);
      int tok = tok_ids[(row >> 5) * 33 + (row & 31)];
      float4 v = *reinterpret_cast<const float4*>(&wemb[(size_t)tok * H + c4]);
      o.x = f2bf(v.x); o.y = f2bf(v.y); o.z = f2bf(v.z); o.w = f2bf(v.w);
    }
    *reinterpret_cast<ushort4*>(&e_bf[(size_t)s * H + c4]) = o;
  }
}

// ---- kernel 2: u[slot,:] = E[slot,:] x WdecT^T (bf16 MFMA) — proven 128^2 structure ----
#define UBM 128
#define UBN 128
#define UBK 64

__global__ __launch_bounds__(256) void udec_gemm_kernel(const u16* __restrict__ A,
                                                        const u16* __restrict__ Bm,
                                                        const int* __restrict__ split,
                                                        const int* __restrict__ nch,
                                                        u16* __restrict__ U) {
  __shared__ int pre[65];
  const int tid = threadIdx.x;
  const int cnt = build_prefix(split, nch, pre, tid);
  const int m0i = blockIdx.y * UBM;
  if (m0i >= cnt) return;
  __shared__ u16 As[UBM * UBK];
  __shared__ u16 Bs[UBN * UBK];
  const int wave = tid >> 6;
  const int lane = tid & 63;
  const int wm = (wave >> 1) * 64;
  const int wn = (wave & 1) * 64;
  const int fr = lane & 15;
  const int fq = lane >> 4;
  const size_t m0 = (size_t)m0i;
  const size_t n0 = (size_t)blockIdx.x * UBN;
  const u16* Abase = A + m0 * H;
  const u16* Bbase = Bm + n0 * H;

  f32x4 acc[4][4];
  const f32x4 z = {0.f, 0.f, 0.f, 0.f};
  #pragma unroll
  for (int i = 0; i < 4; ++i)
    #pragma unroll
    for (int j = 0; j < 4; ++j) acc[i][j] = z;

  for (int k0 = 0; k0 < H; k0 += UBK) {
    #pragma unroll
    for (int i = 0; i < 4; ++i) {
      int e = (i * 256 + tid) * 8;
      int row = e >> 6;
      int col = e & 63;
      __builtin_amdgcn_global_load_lds((gp1_t)(Abase + (size_t)row * H + k0 + col),
                                       (lp3_t)(&As[e]), 16, 0, 0);
      __builtin_amdgcn_global_load_lds((gp1_t)(Bbase + (size_t)row * H + k0 + col),
                                       (lp3_t)(&Bs[e]), 16, 0, 0);
    }
    __syncthreads();
    #pragma unroll
    for (int kk = 0; kk < UBK; kk += 32) {
      bf16x8 af[4], bfr[4];
      #pragma unroll
      for (int mi = 0; mi < 4; ++mi)
        af[mi] = *reinterpret_cast<const bf16x8*>(&As[(wm + mi * 16 + fr) * UBK + kk + fq * 8]);
      #pragma unroll
      for (int ni = 0; ni < 4; ++ni)
        bfr[ni] = *reinterpret_cast<const bf16x8*>(&Bs[(wn + ni * 16 + fr) * UBK + kk + fq * 8]);
      #pragma unroll
      for (int mi = 0; mi < 4; ++mi)
        #pragma unroll
        for (int ni = 0; ni < 4; ++ni)
          acc[mi][ni] = __builtin_amdgcn_mfma_f32_16x16x32_bf16(af[mi], bfr[ni], acc[mi][ni], 0, 0, 0);
    }
    __syncthreads();
  }

  u16* Ubase = U + (m0 + wm) * (size_t)H + n0 + wn;
  #pragma unroll
  for (int mi = 0; mi < 4; ++mi)
    #pragma unroll
    for (int ni = 0; ni < 4; ++ni)
      #pragma unroll
      for (int v = 0; v < 4; ++v)
        Ubase[(size_t)(mi * 16 + fq * 4 + v) * H + ni * 16 + fr] = f2bf(acc[mi][ni][v]);
}

// ---- kernel 3: main GEMM — round-6 gemm8 VERBATIM schedule (PASSED validation) ----
// 256x256 tile, 8 waves, BK=32, 3 LDS buffers, 4 gload_lds/stage, vmcnt(8) counted
// (never drained to 0 in-loop), raw s_barrier. + prefix compaction + coalesced
// LDS-bounce epilogue (round-16 proven concept, ported to 256-col panels).
__device__ __forceinline__ void g8_stage(const u16* __restrict__ Abase,
                                         const u16* __restrict__ Bbase,
                                         int kt, u16* as, u16* bs, int tid) {
  const int rih = tid >> 2;                  // 0..127
  const int s = tid & 3;
  const int ssw = s ^ ((rih >> 1) & 3);      // pre-swizzled global chunk (both-sides)
  const int kelem = kt * 32 + ssw * 8;
  u16* la = as + rih * 32 + s * 8;           // linear dest = wave-base + lane*16B
  u16* lb = bs + rih * 32 + s * 8;
  __builtin_amdgcn_global_load_lds((gp1_t)(Abase + (size_t)rih * H + kelem), (lp3_t)la, 16, 0, 0);
  __builtin_amdgcn_global_load_lds((gp1_t)(Abase + (size_t)(rih + 128) * H + kelem),
                                   (lp3_t)(la + 128 * 32), 16, 0, 0);
  __builtin_amdgcn_global_load_lds((gp1_t)(Bbase + (size_t)rih * H + kelem), (lp3_t)lb, 16, 0, 0);
  __builtin_amdgcn_global_load_lds((gp1_t)(Bbase + (size_t)(rih + 128) * H + kelem),
                                   (lp3_t)(lb + 128 * 32), 16, 0, 0);
}

__global__ __launch_bounds__(512, 1) void gemm8_kernel(const u16* __restrict__ A,
                                                       const u16* __restrict__ Bm,
                                                       const int* __restrict__ split,
                                                       const int* __restrict__ nch,
                                                       float* __restrict__ C) {
  __shared__ int pre[65];
  __shared__ int rowmap[256];
  __shared__ __align__(16) u16 smem[49152];  // 96 KiB: K-loop staging ∪ epilogue bounce
  const int tid = threadIdx.x;
  const int cnt = build_prefix(split, nch, pre, tid);
  const int flat = blockIdx.x;
  const int my = flat / 125;                 // my-major: real tiles are low blockIdx
  const int nx = flat % 125;
  const int m0i = my << 8;
  if (m0i >= cnt) return;                    // uniform per block
  if (tid < 256) rowmap[tid] = (m0i + tid < cnt) ? slot2row(pre, m0i + tid) : -1;
  const int wave = tid >> 6;
  const int lane = tid & 63;
  const int fr = lane & 15;
  const int fq = lane >> 4;
  const int mh = wave >> 2;                  // 0..1  (M half: 128 rows)
  const int wn4 = wave & 3;                  // 0..3  (N quarter: 64 cols)
  const size_t n0 = (size_t)nx * 256;
  const u16* Abase = A + (size_t)m0i * H;
  const u16* Bbase = Bm + n0 * H;
  const int swz = fq ^ ((fr >> 1) & 3);      // read-side swizzle
  const int aoff = (mh * 128 + fr) * 32 + swz * 8;
  const int boff = (wn4 * 64 + fr) * 32 + swz * 8;

  f32x4 acc[8][4];
  const f32x4 z = {0.f, 0.f, 0.f, 0.f};
  #pragma unroll
  for (int i = 0; i < 8; ++i)
    #pragma unroll
    for (int j = 0; j < 4; ++j) acc[i][j] = z;

  u16 *a0 = smem,          *a1 = smem + 8192,  *a2 = smem + 16384;
  u16 *b0 = smem + 24576,  *b1 = smem + 32768, *b2 = smem + 40960;
  g8_stage(Abase, Bbase, 0, a0, b0, tid);
  g8_stage(Abase, Bbase, 1, a1, b1, tid);

  for (int t = 0; t < NT; ++t) {
    // prefetch tile t+2 (dummy reload of tile 0 at tail keeps vmcnt accounting fixed)
    g8_stage(Abase, Bbase, (t + 2 < NT) ? t + 2 : 0, a2, b2, tid);
    // counted wait: 12 outstanding -> 8 leaves exactly tile t's 4 loads retired
    asm volatile("s_waitcnt vmcnt(8)" ::: "memory");
    __builtin_amdgcn_s_barrier();
    __builtin_amdgcn_sched_barrier(0);       // pin ds_reads below the barrier (rule #18)

    bf16x8 av[4], bv[4];
    #pragma unroll
    for (int ni = 0; ni < 4; ++ni)
      bv[ni] = *reinterpret_cast<const bf16x8*>(b0 + boff + ni * 512);
    #pragma unroll
    for (int mi = 0; mi < 4; ++mi)
      av[mi] = *reinterpret_cast<const bf16x8*>(a0 + aoff + mi * 512);
    __builtin_amdgcn_s_setprio(1);
    #pragma unroll
    for (int mi = 0; mi < 4; ++mi)
      #pragma unroll
      for (int ni = 0; ni < 4; ++ni)
        acc[mi][ni] = __builtin_amdgcn_mfma_f32_16x16x32_bf16(av[mi], bv[ni], acc[mi][ni], 0, 0, 0);
    __builtin_amdgcn_s_setprio(0);
    #pragma unroll
    for (int mi = 0; mi < 4; ++mi)
      av[mi] = *reinterpret_cast<const bf16x8*>(a0 + aoff + (mi + 4) * 512);
    __builtin_amdgcn_s_setprio(1);
    #pragma unroll
    for (int mi = 0; mi < 4; ++mi)
      #pragma unroll
      for (int ni = 0; ni < 4; ++ni)
        acc[mi + 4][ni] = __builtin_amdgcn_mfma_f32_16x16x32_bf16(av[mi], bv[ni], acc[mi + 4][ni], 0, 0, 0);
    __builtin_amdgcn_s_setprio(0);

    // own ds_reads of tile t executed -> after barrier, buffer reuse is safe
    asm volatile("s_waitcnt lgkmcnt(0)" ::: "memory");
    __builtin_amdgcn_s_barrier();
    __builtin_amdgcn_sched_barrier(0);
    u16* ta = a0; a0 = a1; a1 = a2; a2 = ta;
    u16* tb = b0; b0 = b1; b1 = b2; b2 = tb;
  }

  // CRITICAL: drain in-flight (dummy) gload_lds into a2/b2 before reusing LDS as bounce
  __syncthreads();

  // ---- coalesced epilogue: bounce acc through LDS (4 chunks of 64 rows x 256 cols) ----
  // acc layout: wave (mh,wn4) holds rows mh*128+mi*16+fq*4+v, cols wn4*64+ni*16+fr.
  float* epil = reinterpret_cast<float*>(smem);   // 64*256*4 = 64 KiB (fits 96 KiB)
  #pragma unroll
  for (int c = 0; c < 4; ++c) {
    const int mhc = c >> 1, cl = c & 1;
    if (mh == mhc) {
      #pragma unroll
      for (int mi2 = 0; mi2 < 4; ++mi2) {
        int mi = cl * 4 + mi2;
        #pragma unroll
        for (int v = 0; v < 4; ++v) {
          int lr = mi2 * 16 + fq * 4 + v;   // local row in [0,64)
          #pragma unroll
          for (int ni = 0; ni < 4; ++ni)
            epil[lr * 256 + wn4 * 64 + ni * 16 + fr] = acc[mi][ni][v];
        }
      }
    }
    __syncthreads();
    #pragma unroll
    for (int i = 0; i < 8; ++i) {
      int idx = i * 512 + tid;
      int row = idx >> 6, q = idx & 63;     // 64 f32x4 per 256-col row
      int orow = rowmap[c * 64 + row];
      if (orow >= 0) {
        f32x4 val = *reinterpret_cast<const f32x4*>(&epil[row * 256 + q * 4]);
        __builtin_nontemporal_store(val, reinterpret_cast<f32x4*>(C + (size_t)orow * V + n0) + q);
      }
    }
    __syncthreads();
  }
}

extern "C" void kernel_launch(void* const* d_in, const int* in_sizes, int n_in,
                              void* d_out, int out_size, void* d_ws, size_t ws_size,
                              hipStream_t stream) {
  const int* tok    = (const int*)d_in[0];    // (4,16,33) int32
  const int* split  = (const int*)d_in[1];    // (4,16) int32
  const int* nch    = (const int*)d_in[2];    // (4,) int32
  // d_in[3] chunk_units, d_in[5] chunk_sos_embedding: provably dead w.r.t. output
  const float* wemb = (const float*)d_in[4];  // (32000,768) f32
  const float* wdec = (const float*)d_in[6];  // (768,768) f32
  float* out = (float*)d_out;                 // (4,16,32,32000) f32

  char* ws = (char*)d_ws;
  u16* wemb_bf = (u16*)ws;                                // 49,152,000 B
  u16* u       = (u16*)(ws + 49152000);                   //  3,145,728 B
  u16* e_bf    = (u16*)(ws + 49152000 + 3145728);         //  3,145,728 B
  u16* wdecT   = (u16*)(ws + 49152000 + 2 * 3145728);     //  1,179,648 B

  prepZ_kernel<<<MROWS + NCONV + 144 + MROWS, 256, 0, stream>>>(wemb, wemb_bf, wdec, wdecT,
                                                                tok, split, nch, e_bf, out);
  udec_gemm_kernel<<<dim3(H / UBN, MROWS / UBM), 256, 0, stream>>>(e_bf, wdecT, split, nch, u);
  gemm8_kernel<<<1000, 512, 0, stream>>>(u, wemb_bf, split, nch, out);
}

// Round 18
// 100.525 us; speedup vs baseline: 1.2403x; 1.2403x over previous
//
#include <hip/hip_runtime.h>

typedef unsigned short u16;
typedef unsigned int u32;
typedef __attribute__((ext_vector_type(4))) float f32x4;
typedef __attribute__((ext_vector_type(8))) short bf16x8;
typedef __attribute__((address_space(1))) const u32* gp1_t;
typedef __attribute__((address_space(3))) u32* lp3_t;

#define H 768
#define V 32000
#define MROWS 2048   // B*C*32 = 4*16*32
#define NPAN 250     // N-panels of 128 cols
#define NGEMM 2000   // 8 M-tiles x 250 N-panels (my-major)
#define NT 24        // 768 / 32

__device__ __forceinline__ u16 f2bf(float f) {
  u32 x = __float_as_uint(f);
  x += 0x7fffu + ((x >> 16) & 1u);   // round-to-nearest-even
  return (u16)(x >> 16);
}

__device__ __forceinline__ bf16x8 pack8(float4 a, float4 b) {
  bf16x8 r;
  r[0] = (short)f2bf(a.x); r[1] = (short)f2bf(a.y);
  r[2] = (short)f2bf(a.z); r[3] = (short)f2bf(a.w);
  r[4] = (short)f2bf(b.x); r[5] = (short)f2bf(b.y);
  r[6] = (short)f2bf(b.z); r[7] = (short)f2bf(b.w);
  return r;
}

// Returns true if this output row is ACTIVE (gemm writes it); inactive rows get zeroed.
__device__ __forceinline__ bool row_active(const int* __restrict__ split,
                                           const int* __restrict__ nch, int row) {
  int b = row >> 9, c = (row >> 5) & 15, t = row & 31;
  return (c < nch[b] && t < split[b * 16 + c]);
}

// Zero one output row with nontemporal f32x4 stores (nth = blockDim.x).
__device__ __forceinline__ void zero_row(float* __restrict__ out, int row, int tid, int nth) {
  const f32x4 z = {0.f, 0.f, 0.f, 0.f};
  f32x4* p = reinterpret_cast<f32x4*>(out + (size_t)row * V);
  for (int i = tid; i < V / 4; i += nth)
    __builtin_nontemporal_store(z, p + i);
}

// Deterministic compaction: active rows sorted by (b,c,t). pre[j] = exclusive prefix
// over the 64 chunks' active counts; pre[64] = cnt. Wave-parallel scan on wave 0.
__device__ __forceinline__ int build_prefix(const int* __restrict__ split,
                                            const int* __restrict__ nch,
                                            int* pre, int tid) {
  if (tid < 64) {
    int b = tid >> 4, c = tid & 15;
    int sz = (c < nch[b]) ? split[tid] : 0;
    sz = sz < 32 ? sz : 32;
    int incl = sz;
    #pragma unroll
    for (int d = 1; d < 64; d <<= 1) {
      int up = __shfl_up(incl, d, 64);
      if (tid >= d) incl += up;
    }
    pre[tid] = incl - sz;              // exclusive prefix
    if (tid == 63) pre[64] = incl;     // total
  }
  __syncthreads();
  return pre[64];
}

__device__ __forceinline__ int slot2row(const int* pre, int s) {
  int lo = 0, hi = 63;
  while (lo < hi) { int mid = (lo + hi + 1) >> 1; if (pre[mid] <= s) lo = mid; else hi = mid - 1; }
  return lo * 32 + (s - pre[lo]);   // (b*16+c)*32 + t
}

// ---- kernel A: {W_dec^T->bf16} + {E gather->bf16} + {zfill riders, rows [1536,2048)} ----
// blocks [0,144): wdecT; [144,2192): egather; [2192,2704): zfill rider.
__global__ void prepA_kernel(const float* __restrict__ wdec, u16* __restrict__ wdecT,
                             const int* __restrict__ tok_ids, const float* __restrict__ wemb,
                             const int* __restrict__ split, const int* __restrict__ nch,
                             u16* __restrict__ e_bf, float* __restrict__ out) {
  if (blockIdx.x < 144) {
    __shared__ float tile[64][65];
    int b = blockIdx.x;
    int hb = (b / 12) * 64, jb = (b % 12) * 64;
    #pragma unroll
    for (int rr = 0; rr < 64; rr += 16) {
      int r = rr + (threadIdx.x >> 4);
      int c = (threadIdx.x & 15) * 4;
      float4 v = *reinterpret_cast<const float4*>(&wdec[(size_t)(hb + r) * H + jb + c]);
      tile[r][c] = v.x; tile[r][c + 1] = v.y; tile[r][c + 2] = v.z; tile[r][c + 3] = v.w;
    }
    __syncthreads();
    #pragma unroll
    for (int rr = 0; rr < 64; rr += 16) {
      int r = rr + (threadIdx.x >> 4);      // j
      int c = (threadIdx.x & 15) * 4;       // h group
      ushort4 o;
      o.x = f2bf(tile[c][r]); o.y = f2bf(tile[c + 1][r]);
      o.z = f2bf(tile[c + 2][r]); o.w = f2bf(tile[c + 3][r]);
      *reinterpret_cast<ushort4*>(&wdecT[(size_t)(jb + r) * H + hb + c]) = o;
    }
  } else if (blockIdx.x < 144 + MROWS) {
    __shared__ int pre[65];
    int tid = threadIdx.x;
    int cnt = build_prefix(split, nch, pre, tid);
    int s = blockIdx.x - 144;
    int c4 = tid * 4;
    if (c4 >= H) return;
    ushort4 o = {0, 0, 0, 0};
    if (s < cnt) {
      int row = slot2row(pre, s);
      int tok = tok_ids[(row >> 5) * 33 + (row & 31)];
      float4 v = *reinterpret_cast<const float4*>(&wemb[(size_t)tok * H + c4]);
      o.x = f2bf(v.x); o.y = f2bf(v.y); o.z = f2bf(v.z); o.w = f2bf(v.w);
    }
    *reinterpret_cast<ushort4*>(&e_bf[(size_t)s * H + c4]) = o;
  } else {
    int row = 1536 + (blockIdx.x - 144 - MROWS);
    if (row_active(split, nch, row)) return;
    zero_row(out, row, threadIdx.x, 256);
  }
}

// ---- kernel B: u = E x WdecT^T (bf16 MFMA) + {zfill riders, rows [1024,1536)} ----
// 1D grid: blocks [0,96): GEMM tile (ntile = b%6, mtile = b/6); [96,608): zfill rider.
#define UBM 128
#define UBN 128
#define UBK 64

__global__ __launch_bounds__(256) void udec_gemm_kernel(const u16* __restrict__ A,
                                                        const u16* __restrict__ Bm,
                                                        const int* __restrict__ split,
                                                        const int* __restrict__ nch,
                                                        u16* __restrict__ U,
                                                        float* __restrict__ out) {
  const int tid = threadIdx.x;
  if (blockIdx.x >= 96) {
    int row = 1024 + (blockIdx.x - 96);
    if (row_active(split, nch, row)) return;
    zero_row(out, row, tid, 256);
    return;
  }
  __shared__ int pre[65];
  const int cnt = build_prefix(split, nch, pre, tid);
  const int m0i = (blockIdx.x / 6) * UBM;
  if (m0i >= cnt) return;
  __shared__ u16 As[UBM * UBK];
  __shared__ u16 Bs[UBN * UBK];
  const int wave = tid >> 6;
  const int lane = tid & 63;
  const int wm = (wave >> 1) * 64;
  const int wn = (wave & 1) * 64;
  const int fr = lane & 15;
  const int fq = lane >> 4;
  const size_t m0 = (size_t)m0i;
  const size_t n0 = (size_t)(blockIdx.x % 6) * UBN;
  const u16* Abase = A + m0 * H;
  const u16* Bbase = Bm + n0 * H;

  f32x4 acc[4][4];
  const f32x4 z = {0.f, 0.f, 0.f, 0.f};
  #pragma unroll
  for (int i = 0; i < 4; ++i)
    #pragma unroll
    for (int j = 0; j < 4; ++j) acc[i][j] = z;

  for (int k0 = 0; k0 < H; k0 += UBK) {
    #pragma unroll
    for (int i = 0; i < 4; ++i) {
      int e = (i * 256 + tid) * 8;
      int row = e >> 6;
      int col = e & 63;
      __builtin_amdgcn_global_load_lds((gp1_t)(Abase + (size_t)row * H + k0 + col),
                                       (lp3_t)(&As[e]), 16, 0, 0);
      __builtin_amdgcn_global_load_lds((gp1_t)(Bbase + (size_t)row * H + k0 + col),
                                       (lp3_t)(&Bs[e]), 16, 0, 0);
    }
    __syncthreads();
    #pragma unroll
    for (int kk = 0; kk < UBK; kk += 32) {
      bf16x8 af[4], bfr[4];
      #pragma unroll
      for (int mi = 0; mi < 4; ++mi)
        af[mi] = *reinterpret_cast<const bf16x8*>(&As[(wm + mi * 16 + fr) * UBK + kk + fq * 8]);
      #pragma unroll
      for (int ni = 0; ni < 4; ++ni)
        bfr[ni] = *reinterpret_cast<const bf16x8*>(&Bs[(wn + ni * 16 + fr) * UBK + kk + fq * 8]);
      #pragma unroll
      for (int mi = 0; mi < 4; ++mi)
        #pragma unroll
        for (int ni = 0; ni < 4; ++ni)
          acc[mi][ni] = __builtin_amdgcn_mfma_f32_16x16x32_bf16(af[mi], bfr[ni], acc[mi][ni], 0, 0, 0);
    }
    __syncthreads();
  }

  u16* Ubase = U + (m0 + wm) * (size_t)H + n0 + wn;
  #pragma unroll
  for (int mi = 0; mi < 4; ++mi)
    #pragma unroll
    for (int ni = 0; ni < 4; ++ni)
      #pragma unroll
      for (int v = 0; v < 4; ++v)
        Ubase[(size_t)(mi * 16 + fq * 4 + v) * H + ni * 16 + fr] = f2bf(acc[mi][ni][v]);
}

// ---- kernel C: FUSED {main GEMM 256x128} + {zfill riders, rows [0,1024)} ----
// Blocks [0,2000): GEMM tile (my-major), 8 waves, BK=32, 2-buffer 2-phase, f32-B
// reg-staged, coalesced LDS-bounce epilogue. Blocks [2000,3024): zfill rider.
__global__ __launch_bounds__(512) void fused_kernel(const u16* __restrict__ A,
                                                    const float* __restrict__ Wf,
                                                    const int* __restrict__ split,
                                                    const int* __restrict__ nch,
                                                    float* __restrict__ C) {
  const int flat = blockIdx.x;
  if (flat >= NGEMM) {
    int row = flat - NGEMM;                  // rows [0,1024)
    if (row_active(split, nch, row)) return;
    zero_row(C, row, threadIdx.x, 512);
    return;
  }
  __shared__ int pre[65];
  __shared__ int rowmap[256];
  __shared__ __align__(16) u16 smem[24576];  // 48 KiB: K-loop staging ∪ epilogue bounce
  u16* const AsB = smem;                     // 2 x 256x32 bf16 = 32 KiB
  u16* const BsB = smem + 16384;             // 2 x 128x32 bf16 = 16 KiB
  const int tid = threadIdx.x;
  const int cnt = build_prefix(split, nch, pre, tid);
  const int my = flat / NPAN;                // my-major: real GEMM tiles are low blockIdx
  const int nx = flat % NPAN;
  const int m0i = my << 8;
  if (m0i >= cnt) return;                    // uniform per block

  const int wave = tid >> 6;
  const int lane = tid & 63;
  const int fr = lane & 15;
  const int fq = lane >> 4;
  const int mh = wave >> 2;                  // 0..1  (M half: 128 rows)
  const int wn4 = wave & 3;                  // 0..3  (N quarter: 32 cols)
  const size_t n0 = (size_t)nx * 128;
  const float* Bfbase = Wf + n0 * H;
  const u16* Abase = A + (size_t)m0i * H;
  // staging thread mapping: rih 0..127, s 0..3 (16B chunks of a 32-elem row)
  const int rih = tid >> 2;
  const int s = tid & 3;
  const int ssw = s ^ ((rih >> 1) & 3);      // pre-swizzled chunk (both-sides swizzle)
  // read-side swizzle: (row>>1)&3 == (fr>>1)&3 for all fragment rows
  const int swz = fq ^ ((fr >> 1) & 3);
  const int aoff = (mh * 128 + fr) * 32 + swz * 8;
  const int boff = (wn4 * 32 + fr) * 32 + swz * 8;

  if (tid < 256) {
    int sl = m0i + tid;
    rowmap[tid] = (sl < cnt) ? slot2row(pre, sl) : -1;
  }

  f32x4 acc[8][2];
  const f32x4 z = {0.f, 0.f, 0.f, 0.f};
  #pragma unroll
  for (int i = 0; i < 8; ++i)
    #pragma unroll
    for (int j = 0; j < 2; ++j) acc[i][j] = z;

  // prologue: stage tile 0 into buffer 0 (A: 2 gload_lds/thread; B: f32->bf16 reg-staged)
  {
    const int kelem = ssw * 8;
    __builtin_amdgcn_global_load_lds((gp1_t)(Abase + (size_t)rih * H + kelem),
                                     (lp3_t)(AsB + rih * 32 + s * 8), 16, 0, 0);
    __builtin_amdgcn_global_load_lds((gp1_t)(Abase + (size_t)(rih + 128) * H + kelem),
                                     (lp3_t)(AsB + (rih + 128) * 32 + s * 8), 16, 0, 0);
    float4 b0 = *reinterpret_cast<const float4*>(Bfbase + (size_t)rih * H + kelem);
    float4 b1 = *reinterpret_cast<const float4*>(Bfbase + (size_t)rih * H + kelem + 4);
    *reinterpret_cast<bf16x8*>(BsB + rih * 32 + s * 8) = pack8(b0, b1);
  }
  __syncthreads();

  for (int t = 0; t < NT; ++t) {
    u16* curA = AsB + (t & 1) * 8192;
    u16* curB = BsB + (t & 1) * 4096;
    u16* nxtA = AsB + ((t + 1) & 1) * 8192;
    u16* nxtB = BsB + ((t + 1) & 1) * 4096;
    const bool more = (t + 1 < NT);
    float4 b0, b1;
    if (more) {
      const int kelem = (t + 1) * 32 + ssw * 8;
      __builtin_amdgcn_global_load_lds((gp1_t)(Abase + (size_t)rih * H + kelem),
                                       (lp3_t)(nxtA + rih * 32 + s * 8), 16, 0, 0);
      __builtin_amdgcn_global_load_lds((gp1_t)(Abase + (size_t)(rih + 128) * H + kelem),
                                       (lp3_t)(nxtA + (rih + 128) * 32 + s * 8), 16, 0, 0);
      b0 = *reinterpret_cast<const float4*>(Bfbase + (size_t)rih * H + kelem);
      b1 = *reinterpret_cast<const float4*>(Bfbase + (size_t)rih * H + kelem + 4);
    }

    bf16x8 av[4], bv[2];
    #pragma unroll
    for (int ni = 0; ni < 2; ++ni)
      bv[ni] = *reinterpret_cast<const bf16x8*>(curB + boff + ni * 512);
    #pragma unroll
    for (int mi = 0; mi < 4; ++mi)
      av[mi] = *reinterpret_cast<const bf16x8*>(curA + aoff + mi * 512);
    __builtin_amdgcn_s_setprio(1);
    #pragma unroll
    for (int mi = 0; mi < 4; ++mi)
      #pragma unroll
      for (int ni = 0; ni < 2; ++ni)
        acc[mi][ni] = __builtin_amdgcn_mfma_f32_16x16x32_bf16(av[mi], bv[ni], acc[mi][ni], 0, 0, 0);
    __builtin_amdgcn_s_setprio(0);
    #pragma unroll
    for (int mi = 0; mi < 4; ++mi)
      av[mi] = *reinterpret_cast<const bf16x8*>(curA + aoff + (mi + 4) * 512);
    __builtin_amdgcn_s_setprio(1);
    #pragma unroll
    for (int mi = 0; mi < 4; ++mi)
      #pragma unroll
      for (int ni = 0; ni < 2; ++ni)
        acc[mi + 4][ni] = __builtin_amdgcn_mfma_f32_16x16x32_bf16(av[mi], bv[ni], acc[mi + 4][ni], 0, 0, 0);
    __builtin_amdgcn_s_setprio(0);

    if (more)
      *reinterpret_cast<bf16x8*>(nxtB + rih * 32 + s * 8) = pack8(b0, b1);
    __syncthreads();   // drains gload_lds(A,t+1) + ds_writes(B,t+1) + all reads of cur
  }

  // ---- coalesced epilogue: bounce acc through LDS (4 chunks of 64 rows x 128 cols) ----
  // acc layout: wave (mh,wn4) holds rows mh*128 + mi*16 + fq*4 + v, cols wn4*32 + ni*16 + fr.
  float* epil = reinterpret_cast<float*>(smem);   // 64*128*4 = 32 KiB (fits staging LDS)
  #pragma unroll
  for (int c = 0; c < 4; ++c) {
    const int mhc = c >> 1, cl = c & 1;
    if (mh == mhc) {
      #pragma unroll
      for (int mi2 = 0; mi2 < 4; ++mi2) {
        int mi = cl * 4 + mi2;
        #pragma unroll
        for (int v = 0; v < 4; ++v) {
          int lr = mi2 * 16 + fq * 4 + v;   // local row in [0,64)
          #pragma unroll
          for (int ni = 0; ni < 2; ++ni)
            epil[lr * 128 + wn4 * 32 + ni * 16 + fr] = acc[mi][ni][v];
        }
      }
    }
    __syncthreads();
    #pragma unroll
    for (int i = 0; i < 4; ++i) {
      int idx = i * 512 + tid;
      int row = idx >> 5, q = idx & 31;
      int orow = rowmap[c * 64 + row];
      if (orow >= 0) {
        f32x4 val = *reinterpret_cast<const f32x4*>(&epil[row * 128 + q * 4]);
        __builtin_nontemporal_store(val, reinterpret_cast<f32x4*>(C + (size_t)orow * V + n0) + q);
      }
    }
    __syncthreads();
  }
}

extern "C" void kernel_launch(void* const* d_in, const int* in_sizes, int n_in,
                              void* d_out, int out_size, void* d_ws, size_t ws_size,
                              hipStream_t stream) {
  const int* tok    = (const int*)d_in[0];    // (4,16,33) int32
  const int* split  = (const int*)d_in[1];    // (4,16) int32
  const int* nch    = (const int*)d_in[2];    // (4,) int32
  // d_in[3] chunk_units, d_in[5] chunk_sos_embedding: provably dead w.r.t. output
  const float* wemb = (const float*)d_in[4];  // (32000,768) f32
  const float* wdec = (const float*)d_in[6];  // (768,768) f32
  float* out = (float*)d_out;                 // (4,16,32,32000) f32

  char* ws = (char*)d_ws;
  u16* u     = (u16*)ws;                      // 3,145,728 B
  u16* e_bf  = (u16*)(ws + 3145728);          // 3,145,728 B
  u16* wdecT = (u16*)(ws + 2 * 3145728);      // 1,179,648 B

  prepA_kernel<<<144 + MROWS + 512, 256, 0, stream>>>(wdec, wdecT, tok, wemb, split, nch, e_bf, out);
  udec_gemm_kernel<<<96 + 512, 256, 0, stream>>>(e_bf, wdecT, split, nch, u, out);
  fused_kernel<<<NGEMM + 1024, 512, 0, stream>>>(u, wemb, split, nch, out);
}

// Round 19
// 98.086 us; speedup vs baseline: 1.2711x; 1.0249x over previous
//
#include <hip/hip_runtime.h>

typedef unsigned short u16;
typedef unsigned int u32;
typedef __attribute__((ext_vector_type(4))) float f32x4;
typedef __attribute__((ext_vector_type(8))) short bf16x8;
typedef __attribute__((address_space(1))) const u32* gp1_t;
typedef __attribute__((address_space(3))) u32* lp3_t;

#define H 768
#define V 32000
#define MROWS 2048   // B*C*32 = 4*16*32
#define NPAN 250     // N-panels of 128 cols
#define NGEMM 2000   // 8 M-tiles x 250 N-panels (my-major)
#define NT 24        // 768 / 32

// zfill split across the 3 kernels (rows of `out`): fused [0,ZF0), udec [ZF0,ZF1),
// prepA [ZF1,MROWS). Pure write-reordering; output bit-identical under any split.
#define ZF0 512
#define ZF1 1408

__device__ __forceinline__ u16 f2bf(float f) {
  u32 x = __float_as_uint(f);
  x += 0x7fffu + ((x >> 16) & 1u);   // round-to-nearest-even
  return (u16)(x >> 16);
}

__device__ __forceinline__ bf16x8 pack8(float4 a, float4 b) {
  bf16x8 r;
  r[0] = (short)f2bf(a.x); r[1] = (short)f2bf(a.y);
  r[2] = (short)f2bf(a.z); r[3] = (short)f2bf(a.w);
  r[4] = (short)f2bf(b.x); r[5] = (short)f2bf(b.y);
  r[6] = (short)f2bf(b.z); r[7] = (short)f2bf(b.w);
  return r;
}

// Returns true if this output row is ACTIVE (gemm writes it); inactive rows get zeroed.
__device__ __forceinline__ bool row_active(const int* __restrict__ split,
                                           const int* __restrict__ nch, int row) {
  int b = row >> 9, c = (row >> 5) & 15, t = row & 31;
  return (c < nch[b] && t < split[b * 16 + c]);
}

// Zero one output row with nontemporal f32x4 stores (nth = blockDim.x).
__device__ __forceinline__ void zero_row(float* __restrict__ out, int row, int tid, int nth) {
  const f32x4 z = {0.f, 0.f, 0.f, 0.f};
  f32x4* p = reinterpret_cast<f32x4*>(out + (size_t)row * V);
  for (int i = tid; i < V / 4; i += nth)
    __builtin_nontemporal_store(z, p + i);
}

// Deterministic compaction: active rows sorted by (b,c,t). pre[j] = exclusive prefix
// over the 64 chunks' active counts; pre[64] = cnt. Wave-parallel scan on wave 0.
__device__ __forceinline__ int build_prefix(const int* __restrict__ split,
                                            const int* __restrict__ nch,
                                            int* pre, int tid) {
  if (tid < 64) {
    int b = tid >> 4, c = tid & 15;
    int sz = (c < nch[b]) ? split[tid] : 0;
    sz = sz < 32 ? sz : 32;
    int incl = sz;
    #pragma unroll
    for (int d = 1; d < 64; d <<= 1) {
      int up = __shfl_up(incl, d, 64);
      if (tid >= d) incl += up;
    }
    pre[tid] = incl - sz;              // exclusive prefix
    if (tid == 63) pre[64] = incl;     // total
  }
  __syncthreads();
  return pre[64];
}

__device__ __forceinline__ int slot2row(const int* pre, int s) {
  int lo = 0, hi = 63;
  while (lo < hi) { int mid = (lo + hi + 1) >> 1; if (pre[mid] <= s) lo = mid; else hi = mid - 1; }
  return lo * 32 + (s - pre[lo]);   // (b*16+c)*32 + t
}

// ---- kernel A: {W_dec^T->bf16} + {E gather->bf16} + {zfill riders, rows [ZF1,2048)} ----
// blocks [0,144): wdecT; [144,2192): egather; [2192,2192+(MROWS-ZF1)): zfill rider.
__global__ void prepA_kernel(const float* __restrict__ wdec, u16* __restrict__ wdecT,
                             const int* __restrict__ tok_ids, const float* __restrict__ wemb,
                             const int* __restrict__ split, const int* __restrict__ nch,
                             u16* __restrict__ e_bf, float* __restrict__ out) {
  if (blockIdx.x < 144) {
    __shared__ float tile[64][65];
    int b = blockIdx.x;
    int hb = (b / 12) * 64, jb = (b % 12) * 64;
    #pragma unroll
    for (int rr = 0; rr < 64; rr += 16) {
      int r = rr + (threadIdx.x >> 4);
      int c = (threadIdx.x & 15) * 4;
      float4 v = *reinterpret_cast<const float4*>(&wdec[(size_t)(hb + r) * H + jb + c]);
      tile[r][c] = v.x; tile[r][c + 1] = v.y; tile[r][c + 2] = v.z; tile[r][c + 3] = v.w;
    }
    __syncthreads();
    #pragma unroll
    for (int rr = 0; rr < 64; rr += 16) {
      int r = rr + (threadIdx.x >> 4);      // j
      int c = (threadIdx.x & 15) * 4;       // h group
      ushort4 o;
      o.x = f2bf(tile[c][r]); o.y = f2bf(tile[c + 1][r]);
      o.z = f2bf(tile[c + 2][r]); o.w = f2bf(tile[c + 3][r]);
      *reinterpret_cast<ushort4*>(&wdecT[(size_t)(jb + r) * H + hb + c]) = o;
    }
  } else if (blockIdx.x < 144 + MROWS) {
    __shared__ int pre[65];
    int tid = threadIdx.x;
    int cnt = build_prefix(split, nch, pre, tid);
    int s = blockIdx.x - 144;
    int c4 = tid * 4;
    if (c4 >= H) return;
    ushort4 o = {0, 0, 0, 0};
    if (s < cnt) {
      int row = slot2row(pre, s);
      int tok = tok_ids[(row >> 5) * 33 + (row & 31)];
      float4 v = *reinterpret_cast<const float4*>(&wemb[(size_t)tok * H + c4]);
      o.x = f2bf(v.x); o.y = f2bf(v.y); o.z = f2bf(v.z); o.w = f2bf(v.w);
    }
    *reinterpret_cast<ushort4*>(&e_bf[(size_t)s * H + c4]) = o;
  } else {
    int row = ZF1 + (blockIdx.x - 144 - MROWS);
    if (row_active(split, nch, row)) return;
    zero_row(out, row, threadIdx.x, 256);
  }
}

// ---- kernel B: u = E x WdecT^T (bf16 MFMA) + {zfill riders, rows [ZF0,ZF1)} ----
// 1D grid: blocks [0,96): GEMM tile (ntile = b%6, mtile = b/6); [96,96+(ZF1-ZF0)): rider.
#define UBM 128
#define UBN 128
#define UBK 64

__global__ __launch_bounds__(256) void udec_gemm_kernel(const u16* __restrict__ A,
                                                        const u16* __restrict__ Bm,
                                                        const int* __restrict__ split,
                                                        const int* __restrict__ nch,
                                                        u16* __restrict__ U,
                                                        float* __restrict__ out) {
  const int tid = threadIdx.x;
  if (blockIdx.x >= 96) {
    int row = ZF0 + (blockIdx.x - 96);
    if (row_active(split, nch, row)) return;
    zero_row(out, row, tid, 256);
    return;
  }
  __shared__ int pre[65];
  const int cnt = build_prefix(split, nch, pre, tid);
  const int m0i = (blockIdx.x / 6) * UBM;
  if (m0i >= cnt) return;
  __shared__ u16 As[UBM * UBK];
  __shared__ u16 Bs[UBN * UBK];
  const int wave = tid >> 6;
  const int lane = tid & 63;
  const int wm = (wave >> 1) * 64;
  const int wn = (wave & 1) * 64;
  const int fr = lane & 15;
  const int fq = lane >> 4;
  const size_t m0 = (size_t)m0i;
  const size_t n0 = (size_t)(blockIdx.x % 6) * UBN;
  const u16* Abase = A + m0 * H;
  const u16* Bbase = Bm + n0 * H;

  f32x4 acc[4][4];
  const f32x4 z = {0.f, 0.f, 0.f, 0.f};
  #pragma unroll
  for (int i = 0; i < 4; ++i)
    #pragma unroll
    for (int j = 0; j < 4; ++j) acc[i][j] = z;

  for (int k0 = 0; k0 < H; k0 += UBK) {
    #pragma unroll
    for (int i = 0; i < 4; ++i) {
      int e = (i * 256 + tid) * 8;
      int row = e >> 6;
      int col = e & 63;
      __builtin_amdgcn_global_load_lds((gp1_t)(Abase + (size_t)row * H + k0 + col),
                                       (lp3_t)(&As[e]), 16, 0, 0);
      __builtin_amdgcn_global_load_lds((gp1_t)(Bbase + (size_t)row * H + k0 + col),
                                       (lp3_t)(&Bs[e]), 16, 0, 0);
    }
    __syncthreads();
    #pragma unroll
    for (int kk = 0; kk < UBK; kk += 32) {
      bf16x8 af[4], bfr[4];
      #pragma unroll
      for (int mi = 0; mi < 4; ++mi)
        af[mi] = *reinterpret_cast<const bf16x8*>(&As[(wm + mi * 16 + fr) * UBK + kk + fq * 8]);
      #pragma unroll
      for (int ni = 0; ni < 4; ++ni)
        bfr[ni] = *reinterpret_cast<const bf16x8*>(&Bs[(wn + ni * 16 + fr) * UBK + kk + fq * 8]);
      #pragma unroll
      for (int mi = 0; mi < 4; ++mi)
        #pragma unroll
        for (int ni = 0; ni < 4; ++ni)
          acc[mi][ni] = __builtin_amdgcn_mfma_f32_16x16x32_bf16(af[mi], bfr[ni], acc[mi][ni], 0, 0, 0);
    }
    __syncthreads();
  }

  u16* Ubase = U + (m0 + wm) * (size_t)H + n0 + wn;
  #pragma unroll
  for (int mi = 0; mi < 4; ++mi)
    #pragma unroll
    for (int ni = 0; ni < 4; ++ni)
      #pragma unroll
      for (int v = 0; v < 4; ++v)
        Ubase[(size_t)(mi * 16 + fq * 4 + v) * H + ni * 16 + fr] = f2bf(acc[mi][ni][v]);
}

// ---- kernel C: FUSED {main GEMM 256x128} + {zfill riders, rows [0,ZF0)} ----
// Blocks [0,2000): GEMM tile (my-major), 8 waves, BK=32, 2-buffer 2-phase, f32-B
// reg-staged, coalesced LDS-bounce epilogue. Blocks [2000,2000+ZF0): zfill rider.
__global__ __launch_bounds__(512) void fused_kernel(const u16* __restrict__ A,
                                                    const float* __restrict__ Wf,
                                                    const int* __restrict__ split,
                                                    const int* __restrict__ nch,
                                                    float* __restrict__ C) {
  const int flat = blockIdx.x;
  if (flat >= NGEMM) {
    int row = flat - NGEMM;                  // rows [0,ZF0)
    if (row_active(split, nch, row)) return;
    zero_row(C, row, threadIdx.x, 512);
    return;
  }
  __shared__ int pre[65];
  __shared__ int rowmap[256];
  __shared__ __align__(16) u16 smem[24576];  // 48 KiB: K-loop staging ∪ epilogue bounce
  u16* const AsB = smem;                     // 2 x 256x32 bf16 = 32 KiB
  u16* const BsB = smem + 16384;             // 2 x 128x32 bf16 = 16 KiB
  const int tid = threadIdx.x;
  const int cnt = build_prefix(split, nch, pre, tid);
  const int my = flat / NPAN;                // my-major: real GEMM tiles are low blockIdx
  const int nx = flat % NPAN;
  const int m0i = my << 8;
  if (m0i >= cnt) return;                    // uniform per block

  const int wave = tid >> 6;
  const int lane = tid & 63;
  const int fr = lane & 15;
  const int fq = lane >> 4;
  const int mh = wave >> 2;                  // 0..1  (M half: 128 rows)
  const int wn4 = wave & 3;                  // 0..3  (N quarter: 32 cols)
  const size_t n0 = (size_t)nx * 128;
  const float* Bfbase = Wf + n0 * H;
  const u16* Abase = A + (size_t)m0i * H;
  // staging thread mapping: rih 0..127, s 0..3 (16B chunks of a 32-elem row)
  const int rih = tid >> 2;
  const int s = tid & 3;
  const int ssw = s ^ ((rih >> 1) & 3);      // pre-swizzled chunk (both-sides swizzle)
  // read-side swizzle: (row>>1)&3 == (fr>>1)&3 for all fragment rows
  const int swz = fq ^ ((fr >> 1) & 3);
  const int aoff = (mh * 128 + fr) * 32 + swz * 8;
  const int boff = (wn4 * 32 + fr) * 32 + swz * 8;

  if (tid < 256) {
    int sl = m0i + tid;
    rowmap[tid] = (sl < cnt) ? slot2row(pre, sl) : -1;
  }

  f32x4 acc[8][2];
  const f32x4 z = {0.f, 0.f, 0.f, 0.f};
  #pragma unroll
  for (int i = 0; i < 8; ++i)
    #pragma unroll
    for (int j = 0; j < 2; ++j) acc[i][j] = z;

  // prologue: stage tile 0 into buffer 0 (A: 2 gload_lds/thread; B: f32->bf16 reg-staged)
  {
    const int kelem = ssw * 8;
    __builtin_amdgcn_global_load_lds((gp1_t)(Abase + (size_t)rih * H + kelem),
                                     (lp3_t)(AsB + rih * 32 + s * 8), 16, 0, 0);
    __builtin_amdgcn_global_load_lds((gp1_t)(Abase + (size_t)(rih + 128) * H + kelem),
                                     (lp3_t)(AsB + (rih + 128) * 32 + s * 8), 16, 0, 0);
    float4 b0 = *reinterpret_cast<const float4*>(Bfbase + (size_t)rih * H + kelem);
    float4 b1 = *reinterpret_cast<const float4*>(Bfbase + (size_t)rih * H + kelem + 4);
    *reinterpret_cast<bf16x8*>(BsB + rih * 32 + s * 8) = pack8(b0, b1);
  }
  __syncthreads();

  for (int t = 0; t < NT; ++t) {
    u16* curA = AsB + (t & 1) * 8192;
    u16* curB = BsB + (t & 1) * 4096;
    u16* nxtA = AsB + ((t + 1) & 1) * 8192;
    u16* nxtB = BsB + ((t + 1) & 1) * 4096;
    const bool more = (t + 1 < NT);
    float4 b0, b1;
    if (more) {
      const int kelem = (t + 1) * 32 + ssw * 8;
      __builtin_amdgcn_global_load_lds((gp1_t)(Abase + (size_t)rih * H + kelem),
                                       (lp3_t)(nxtA + rih * 32 + s * 8), 16, 0, 0);
      __builtin_amdgcn_global_load_lds((gp1_t)(Abase + (size_t)(rih + 128) * H + kelem),
                                       (lp3_t)(nxtA + (rih + 128) * 32 + s * 8), 16, 0, 0);
      b0 = *reinterpret_cast<const float4*>(Bfbase + (size_t)rih * H + kelem);
      b1 = *reinterpret_cast<const float4*>(Bfbase + (size_t)rih * H + kelem + 4);
    }

    bf16x8 av[4], bv[2];
    #pragma unroll
    for (int ni = 0; ni < 2; ++ni)
      bv[ni] = *reinterpret_cast<const bf16x8*>(curB + boff + ni * 512);
    #pragma unroll
    for (int mi = 0; mi < 4; ++mi)
      av[mi] = *reinterpret_cast<const bf16x8*>(curA + aoff + mi * 512);
    __builtin_amdgcn_s_setprio(1);
    #pragma unroll
    for (int mi = 0; mi < 4; ++mi)
      #pragma unroll
      for (int ni = 0; ni < 2; ++ni)
        acc[mi][ni] = __builtin_amdgcn_mfma_f32_16x16x32_bf16(av[mi], bv[ni], acc[mi][ni], 0, 0, 0);
    __builtin_amdgcn_s_setprio(0);
    #pragma unroll
    for (int mi = 0; mi < 4; ++mi)
      av[mi] = *reinterpret_cast<const bf16x8*>(curA + aoff + (mi + 4) * 512);
    __builtin_amdgcn_s_setprio(1);
    #pragma unroll
    for (int mi = 0; mi < 4; ++mi)
      #pragma unroll
      for (int ni = 0; ni < 2; ++ni)
        acc[mi + 4][ni] = __builtin_amdgcn_mfma_f32_16x16x32_bf16(av[mi], bv[ni], acc[mi + 4][ni], 0, 0, 0);
    __builtin_amdgcn_s_setprio(0);

    if (more)
      *reinterpret_cast<bf16x8*>(nxtB + rih * 32 + s * 8) = pack8(b0, b1);
    __syncthreads();   // drains gload_lds(A,t+1) + ds_writes(B,t+1) + all reads of cur
  }

  // ---- coalesced epilogue: bounce acc through LDS (4 chunks of 64 rows x 128 cols) ----
  // acc layout: wave (mh,wn4) holds rows mh*128 + mi*16 + fq*4 + v, cols wn4*32 + ni*16 + fr.
  float* epil = reinterpret_cast<float*>(smem);   // 64*128*4 = 32 KiB (fits staging LDS)
  #pragma unroll
  for (int c = 0; c < 4; ++c) {
    const int mhc = c >> 1, cl = c & 1;
    if (mh == mhc) {
      #pragma unroll
      for (int mi2 = 0; mi2 < 4; ++mi2) {
        int mi = cl * 4 + mi2;
        #pragma unroll
        for (int v = 0; v < 4; ++v) {
          int lr = mi2 * 16 + fq * 4 + v;   // local row in [0,64)
          #pragma unroll
          for (int ni = 0; ni < 2; ++ni)
            epil[lr * 128 + wn4 * 32 + ni * 16 + fr] = acc[mi][ni][v];
        }
      }
    }
    __syncthreads();
    #pragma unroll
    for (int i = 0; i < 4; ++i) {
      int idx = i * 512 + tid;
      int row = idx >> 5, q = idx & 31;
      int orow = rowmap[c * 64 + row];
      if (orow >= 0) {
        f32x4 val = *reinterpret_cast<const f32x4*>(&epil[row * 128 + q * 4]);
        __builtin_nontemporal_store(val, reinterpret_cast<f32x4*>(C + (size_t)orow * V + n0) + q);
      }
    }
    __syncthreads();
  }
}

extern "C" void kernel_launch(void* const* d_in, const int* in_sizes, int n_in,
                              void* d_out, int out_size, void* d_ws, size_t ws_size,
                              hipStream_t stream) {
  const int* tok    = (const int*)d_in[0];    // (4,16,33) int32
  const int* split  = (const int*)d_in[1];    // (4,16) int32
  const int* nch    = (const int*)d_in[2];    // (4,) int32
  // d_in[3] chunk_units, d_in[5] chunk_sos_embedding: provably dead w.r.t. output
  const float* wemb = (const float*)d_in[4];  // (32000,768) f32
  const float* wdec = (const float*)d_in[6];  // (768,768) f32
  float* out = (float*)d_out;                 // (4,16,32,32000) f32

  char* ws = (char*)d_ws;
  u16* u     = (u16*)ws;                      // 3,145,728 B
  u16* e_bf  = (u16*)(ws + 3145728);          // 3,145,728 B
  u16* wdecT = (u16*)(ws + 2 * 3145728);      // 1,179,648 B

  prepA_kernel<<<144 + MROWS + (MROWS - ZF1), 256, 0, stream>>>(wdec, wdecT, tok, wemb,
                                                                split, nch, e_bf, out);
  udec_gemm_kernel<<<96 + (ZF1 - ZF0), 256, 0, stream>>>(e_bf, wdecT, split, nch, u, out);
  fused_kernel<<<NGEMM + ZF0, 512, 0, stream>>>(u, wemb, split, nch, out);
}

// Round 20
// 94.392 us; speedup vs baseline: 1.3209x; 1.0391x over previous
//
#include <hip/hip_runtime.h>

typedef unsigned short u16;
typedef unsigned int u32;
typedef __attribute__((ext_vector_type(4))) float f32x4;
typedef __attribute__((ext_vector_type(8))) short bf16x8;
typedef __attribute__((address_space(1))) const u32* gp1_t;
typedef __attribute__((address_space(3))) u32* lp3_t;

#define H 768
#define V 32000
#define MROWS 2048   // B*C*32 = 4*16*32
#define NPAN 250     // N-panels of 128 cols
#define NGEMM 2000   // 8 M-tiles x 250 N-panels (my-major)
#define NT 24        // 768 / 32

// zfill split across the 3 kernels (rows of `out`): fused [0,ZF0), udec [ZF0,ZF1),
// prepA [ZF1,MROWS). Pure write-reordering; output bit-identical under any split.
#define ZF0 512
#define ZF1 1408

__device__ __forceinline__ u16 f2bf(float f) {
  u32 x = __float_as_uint(f);
  x += 0x7fffu + ((x >> 16) & 1u);   // round-to-nearest-even
  return (u16)(x >> 16);
}

// Hardware packed f32->bf16 (RNE), 2 elems per instruction. No builtin on gfx950
// (m240) -> inline asm. Replaces 3-op/elem bit-math in the hot B-staging path.
__device__ __forceinline__ u32 cvtpk(float lo, float hi) {
  u32 r;
  asm("v_cvt_pk_bf16_f32 %0, %1, %2" : "=v"(r) : "v"(lo), "v"(hi));
  return r;
}

__device__ __forceinline__ bf16x8 pack8(float4 a, float4 b) {
  union { u32 w[4]; bf16x8 v; } u;
  u.w[0] = cvtpk(a.x, a.y);   // lo = elem0, hi = elem1
  u.w[1] = cvtpk(a.z, a.w);
  u.w[2] = cvtpk(b.x, b.y);
  u.w[3] = cvtpk(b.z, b.w);
  return u.v;
}

// Returns true if this output row is ACTIVE (gemm writes it); inactive rows get zeroed.
__device__ __forceinline__ bool row_active(const int* __restrict__ split,
                                           const int* __restrict__ nch, int row) {
  int b = row >> 9, c = (row >> 5) & 15, t = row & 31;
  return (c < nch[b] && t < split[b * 16 + c]);
}

// Zero one output row with nontemporal f32x4 stores (nth = blockDim.x).
__device__ __forceinline__ void zero_row(float* __restrict__ out, int row, int tid, int nth) {
  const f32x4 z = {0.f, 0.f, 0.f, 0.f};
  f32x4* p = reinterpret_cast<f32x4*>(out + (size_t)row * V);
  for (int i = tid; i < V / 4; i += nth)
    __builtin_nontemporal_store(z, p + i);
}

// Deterministic compaction: active rows sorted by (b,c,t). pre[j] = exclusive prefix
// over the 64 chunks' active counts; pre[64] = cnt. Wave-parallel scan on wave 0.
__device__ __forceinline__ int build_prefix(const int* __restrict__ split,
                                            const int* __restrict__ nch,
                                            int* pre, int tid) {
  if (tid < 64) {
    int b = tid >> 4, c = tid & 15;
    int sz = (c < nch[b]) ? split[tid] : 0;
    sz = sz < 32 ? sz : 32;
    int incl = sz;
    #pragma unroll
    for (int d = 1; d < 64; d <<= 1) {
      int up = __shfl_up(incl, d, 64);
      if (tid >= d) incl += up;
    }
    pre[tid] = incl - sz;              // exclusive prefix
    if (tid == 63) pre[64] = incl;     // total
  }
  __syncthreads();
  return pre[64];
}

__device__ __forceinline__ int slot2row(const int* pre, int s) {
  int lo = 0, hi = 63;
  while (lo < hi) { int mid = (lo + hi + 1) >> 1; if (pre[mid] <= s) lo = mid; else hi = mid - 1; }
  return lo * 32 + (s - pre[lo]);   // (b*16+c)*32 + t
}

// ---- kernel A: {W_dec^T->bf16} + {E gather->bf16} + {zfill riders, rows [ZF1,2048)} ----
// blocks [0,144): wdecT; [144,2192): egather; [2192,2192+(MROWS-ZF1)): zfill rider.
__global__ void prepA_kernel(const float* __restrict__ wdec, u16* __restrict__ wdecT,
                             const int* __restrict__ tok_ids, const float* __restrict__ wemb,
                             const int* __restrict__ split, const int* __restrict__ nch,
                             u16* __restrict__ e_bf, float* __restrict__ out) {
  if (blockIdx.x < 144) {
    __shared__ float tile[64][65];
    int b = blockIdx.x;
    int hb = (b / 12) * 64, jb = (b % 12) * 64;
    #pragma unroll
    for (int rr = 0; rr < 64; rr += 16) {
      int r = rr + (threadIdx.x >> 4);
      int c = (threadIdx.x & 15) * 4;
      float4 v = *reinterpret_cast<const float4*>(&wdec[(size_t)(hb + r) * H + jb + c]);
      tile[r][c] = v.x; tile[r][c + 1] = v.y; tile[r][c + 2] = v.z; tile[r][c + 3] = v.w;
    }
    __syncthreads();
    #pragma unroll
    for (int rr = 0; rr < 64; rr += 16) {
      int r = rr + (threadIdx.x >> 4);      // j
      int c = (threadIdx.x & 15) * 4;       // h group
      ushort4 o;
      o.x = f2bf(tile[c][r]); o.y = f2bf(tile[c + 1][r]);
      o.z = f2bf(tile[c + 2][r]); o.w = f2bf(tile[c + 3][r]);
      *reinterpret_cast<ushort4*>(&wdecT[(size_t)(jb + r) * H + hb + c]) = o;
    }
  } else if (blockIdx.x < 144 + MROWS) {
    __shared__ int pre[65];
    int tid = threadIdx.x;
    int cnt = build_prefix(split, nch, pre, tid);
    int s = blockIdx.x - 144;
    int c4 = tid * 4;
    if (c4 >= H) return;
    ushort4 o = {0, 0, 0, 0};
    if (s < cnt) {
      int row = slot2row(pre, s);
      int tok = tok_ids[(row >> 5) * 33 + (row & 31)];
      float4 v = *reinterpret_cast<const float4*>(&wemb[(size_t)tok * H + c4]);
      o.x = f2bf(v.x); o.y = f2bf(v.y); o.z = f2bf(v.z); o.w = f2bf(v.w);
    }
    *reinterpret_cast<ushort4*>(&e_bf[(size_t)s * H + c4]) = o;
  } else {
    int row = ZF1 + (blockIdx.x - 144 - MROWS);
    if (row_active(split, nch, row)) return;
    zero_row(out, row, threadIdx.x, 256);
  }
}

// ---- kernel B: u = E x WdecT^T (bf16 MFMA) + {zfill riders, rows [ZF0,ZF1)} ----
// 1D grid: blocks [0,96): GEMM tile (ntile = b%6, mtile = b/6); [96,96+(ZF1-ZF0)): rider.
#define UBM 128
#define UBN 128
#define UBK 64

__global__ __launch_bounds__(256) void udec_gemm_kernel(const u16* __restrict__ A,
                                                        const u16* __restrict__ Bm,
                                                        const int* __restrict__ split,
                                                        const int* __restrict__ nch,
                                                        u16* __restrict__ U,
                                                        float* __restrict__ out) {
  const int tid = threadIdx.x;
  if (blockIdx.x >= 96) {
    int row = ZF0 + (blockIdx.x - 96);
    if (row_active(split, nch, row)) return;
    zero_row(out, row, tid, 256);
    return;
  }
  __shared__ int pre[65];
  const int cnt = build_prefix(split, nch, pre, tid);
  const int m0i = (blockIdx.x / 6) * UBM;
  if (m0i >= cnt) return;
  __shared__ u16 As[UBM * UBK];
  __shared__ u16 Bs[UBN * UBK];
  const int wave = tid >> 6;
  const int lane = tid & 63;
  const int wm = (wave >> 1) * 64;
  const int wn = (wave & 1) * 64;
  const int fr = lane & 15;
  const int fq = lane >> 4;
  const size_t m0 = (size_t)m0i;
  const size_t n0 = (size_t)(blockIdx.x % 6) * UBN;
  const u16* Abase = A + m0 * H;
  const u16* Bbase = Bm + n0 * H;

  f32x4 acc[4][4];
  const f32x4 z = {0.f, 0.f, 0.f, 0.f};
  #pragma unroll
  for (int i = 0; i < 4; ++i)
    #pragma unroll
    for (int j = 0; j < 4; ++j) acc[i][j] = z;

  for (int k0 = 0; k0 < H; k0 += UBK) {
    #pragma unroll
    for (int i = 0; i < 4; ++i) {
      int e = (i * 256 + tid) * 8;
      int row = e >> 6;
      int col = e & 63;
      __builtin_amdgcn_global_load_lds((gp1_t)(Abase + (size_t)row * H + k0 + col),
                                       (lp3_t)(&As[e]), 16, 0, 0);
      __builtin_amdgcn_global_load_lds((gp1_t)(Bbase + (size_t)row * H + k0 + col),
                                       (lp3_t)(&Bs[e]), 16, 0, 0);
    }
    __syncthreads();
    #pragma unroll
    for (int kk = 0; kk < UBK; kk += 32) {
      bf16x8 af[4], bfr[4];
      #pragma unroll
      for (int mi = 0; mi < 4; ++mi)
        af[mi] = *reinterpret_cast<const bf16x8*>(&As[(wm + mi * 16 + fr) * UBK + kk + fq * 8]);
      #pragma unroll
      for (int ni = 0; ni < 4; ++ni)
        bfr[ni] = *reinterpret_cast<const bf16x8*>(&Bs[(wn + ni * 16 + fr) * UBK + kk + fq * 8]);
      #pragma unroll
      for (int mi = 0; mi < 4; ++mi)
        #pragma unroll
        for (int ni = 0; ni < 4; ++ni)
          acc[mi][ni] = __builtin_amdgcn_mfma_f32_16x16x32_bf16(af[mi], bfr[ni], acc[mi][ni], 0, 0, 0);
    }
    __syncthreads();
  }

  u16* Ubase = U + (m0 + wm) * (size_t)H + n0 + wn;
  #pragma unroll
  for (int mi = 0; mi < 4; ++mi)
    #pragma unroll
    for (int ni = 0; ni < 4; ++ni)
      #pragma unroll
      for (int v = 0; v < 4; ++v)
        Ubase[(size_t)(mi * 16 + fq * 4 + v) * H + ni * 16 + fr] = f2bf(acc[mi][ni][v]);
}

// ---- kernel C: FUSED {main GEMM 256x128} + {zfill riders, rows [0,ZF0)} ----
// Blocks [0,2000): GEMM tile (my-major), 8 waves, BK=32, 2-buffer 2-phase, f32-B
// reg-staged (cvt_pk packing), coalesced LDS-bounce epilogue. Blocks [2000,+ZF0): rider.
__global__ __launch_bounds__(512) void fused_kernel(const u16* __restrict__ A,
                                                    const float* __restrict__ Wf,
                                                    const int* __restrict__ split,
                                                    const int* __restrict__ nch,
                                                    float* __restrict__ C) {
  const int flat = blockIdx.x;
  if (flat >= NGEMM) {
    int row = flat - NGEMM;                  // rows [0,ZF0)
    if (row_active(split, nch, row)) return;
    zero_row(C, row, threadIdx.x, 512);
    return;
  }
  __shared__ int pre[65];
  __shared__ int rowmap[256];
  __shared__ __align__(16) u16 smem[24576];  // 48 KiB: K-loop staging ∪ epilogue bounce
  u16* const AsB = smem;                     // 2 x 256x32 bf16 = 32 KiB
  u16* const BsB = smem + 16384;             // 2 x 128x32 bf16 = 16 KiB
  const int tid = threadIdx.x;
  const int cnt = build_prefix(split, nch, pre, tid);
  const int my = flat / NPAN;                // my-major: real GEMM tiles are low blockIdx
  const int nx = flat % NPAN;
  const int m0i = my << 8;
  if (m0i >= cnt) return;                    // uniform per block

  const int wave = tid >> 6;
  const int lane = tid & 63;
  const int fr = lane & 15;
  const int fq = lane >> 4;
  const int mh = wave >> 2;                  // 0..1  (M half: 128 rows)
  const int wn4 = wave & 3;                  // 0..3  (N quarter: 32 cols)
  const size_t n0 = (size_t)nx * 128;
  const float* Bfbase = Wf + n0 * H;
  const u16* Abase = A + (size_t)m0i * H;
  // staging thread mapping: rih 0..127, s 0..3 (16B chunks of a 32-elem row)
  const int rih = tid >> 2;
  const int s = tid & 3;
  const int ssw = s ^ ((rih >> 1) & 3);      // pre-swizzled chunk (both-sides swizzle)
  // read-side swizzle: (row>>1)&3 == (fr>>1)&3 for all fragment rows
  const int swz = fq ^ ((fr >> 1) & 3);
  const int aoff = (mh * 128 + fr) * 32 + swz * 8;
  const int boff = (wn4 * 32 + fr) * 32 + swz * 8;

  if (tid < 256) {
    int sl = m0i + tid;
    rowmap[tid] = (sl < cnt) ? slot2row(pre, sl) : -1;
  }

  f32x4 acc[8][2];
  const f32x4 z = {0.f, 0.f, 0.f, 0.f};
  #pragma unroll
  for (int i = 0; i < 8; ++i)
    #pragma unroll
    for (int j = 0; j < 2; ++j) acc[i][j] = z;

  // prologue: stage tile 0 into buffer 0 (A: 2 gload_lds/thread; B: f32->bf16 reg-staged)
  {
    const int kelem = ssw * 8;
    __builtin_amdgcn_global_load_lds((gp1_t)(Abase + (size_t)rih * H + kelem),
                                     (lp3_t)(AsB + rih * 32 + s * 8), 16, 0, 0);
    __builtin_amdgcn_global_load_lds((gp1_t)(Abase + (size_t)(rih + 128) * H + kelem),
                                     (lp3_t)(AsB + (rih + 128) * 32 + s * 8), 16, 0, 0);
    float4 b0 = *reinterpret_cast<const float4*>(Bfbase + (size_t)rih * H + kelem);
    float4 b1 = *reinterpret_cast<const float4*>(Bfbase + (size_t)rih * H + kelem + 4);
    *reinterpret_cast<bf16x8*>(BsB + rih * 32 + s * 8) = pack8(b0, b1);
  }
  __syncthreads();

  for (int t = 0; t < NT; ++t) {
    u16* curA = AsB + (t & 1) * 8192;
    u16* curB = BsB + (t & 1) * 4096;
    u16* nxtA = AsB + ((t + 1) & 1) * 8192;
    u16* nxtB = BsB + ((t + 1) & 1) * 4096;
    const bool more = (t + 1 < NT);
    float4 b0, b1;
    if (more) {
      const int kelem = (t + 1) * 32 + ssw * 8;
      __builtin_amdgcn_global_load_lds((gp1_t)(Abase + (size_t)rih * H + kelem),
                                       (lp3_t)(nxtA + rih * 32 + s * 8), 16, 0, 0);
      __builtin_amdgcn_global_load_lds((gp1_t)(Abase + (size_t)(rih + 128) * H + kelem),
                                       (lp3_t)(nxtA + (rih + 128) * 32 + s * 8), 16, 0, 0);
      b0 = *reinterpret_cast<const float4*>(Bfbase + (size_t)rih * H + kelem);
      b1 = *reinterpret_cast<const float4*>(Bfbase + (size_t)rih * H + kelem + 4);
    }

    bf16x8 av[4], bv[2];
    #pragma unroll
    for (int ni = 0; ni < 2; ++ni)
      bv[ni] = *reinterpret_cast<const bf16x8*>(curB + boff + ni * 512);
    #pragma unroll
    for (int mi = 0; mi < 4; ++mi)
      av[mi] = *reinterpret_cast<const bf16x8*>(curA + aoff + mi * 512);
    __builtin_amdgcn_s_setprio(1);
    #pragma unroll
    for (int mi = 0; mi < 4; ++mi)
      #pragma unroll
      for (int ni = 0; ni < 2; ++ni)
        acc[mi][ni] = __builtin_amdgcn_mfma_f32_16x16x32_bf16(av[mi], bv[ni], acc[mi][ni], 0, 0, 0);
    __builtin_amdgcn_s_setprio(0);
    #pragma unroll
    for (int mi = 0; mi < 4; ++mi)
      av[mi] = *reinterpret_cast<const bf16x8*>(curA + aoff + (mi + 4) * 512);
    __builtin_amdgcn_s_setprio(1);
    #pragma unroll
    for (int mi = 0; mi < 4; ++mi)
      #pragma unroll
      for (int ni = 0; ni < 2; ++ni)
        acc[mi + 4][ni] = __builtin_amdgcn_mfma_f32_16x16x32_bf16(av[mi], bv[ni], acc[mi + 4][ni], 0, 0, 0);
    __builtin_amdgcn_s_setprio(0);

    if (more)
      *reinterpret_cast<bf16x8*>(nxtB + rih * 32 + s * 8) = pack8(b0, b1);
    __syncthreads();   // drains gload_lds(A,t+1) + ds_writes(B,t+1) + all reads of cur
  }

  // ---- coalesced epilogue: bounce acc through LDS (4 chunks of 64 rows x 128 cols) ----
  // acc layout: wave (mh,wn4) holds rows mh*128 + mi*16 + fq*4 + v, cols wn4*32 + ni*16 + fr.
  float* epil = reinterpret_cast<float*>(smem);   // 64*128*4 = 32 KiB (fits staging LDS)
  #pragma unroll
  for (int c = 0; c < 4; ++c) {
    const int mhc = c >> 1, cl = c & 1;
    if (mh == mhc) {
      #pragma unroll
      for (int mi2 = 0; mi2 < 4; ++mi2) {
        int mi = cl * 4 + mi2;
        #pragma unroll
        for (int v = 0; v < 4; ++v) {
          int lr = mi2 * 16 + fq * 4 + v;   // local row in [0,64)
          #pragma unroll
          for (int ni = 0; ni < 2; ++ni)
            epil[lr * 128 + wn4 * 32 + ni * 16 + fr] = acc[mi][ni][v];
        }
      }
    }
    __syncthreads();
    #pragma unroll
    for (int i = 0; i < 4; ++i) {
      int idx = i * 512 + tid;
      int row = idx >> 5, q = idx & 31;
      int orow = rowmap[c * 64 + row];
      if (orow >= 0) {
        f32x4 val = *reinterpret_cast<const f32x4*>(&epil[row * 128 + q * 4]);
        __builtin_nontemporal_store(val, reinterpret_cast<f32x4*>(C + (size_t)orow * V + n0) + q);
      }
    }
    __syncthreads();
  }
}

extern "C" void kernel_launch(void* const* d_in, const int* in_sizes, int n_in,
                              void* d_out, int out_size, void* d_ws, size_t ws_size,
                              hipStream_t stream) {
  const int* tok    = (const int*)d_in[0];    // (4,16,33) int32
  const int* split  = (const int*)d_in[1];    // (4,16) int32
  const int* nch    = (const int*)d_in[2];    // (4,) int32
  // d_in[3] chunk_units, d_in[5] chunk_sos_embedding: provably dead w.r.t. output
  const float* wemb = (const float*)d_in[4];  // (32000,768) f32
  const float* wdec = (const float*)d_in[6];  // (768,768) f32
  float* out = (float*)d_out;                 // (4,16,32,32000) f32

  char* ws = (char*)d_ws;
  u16* u     = (u16*)ws;                      // 3,145,728 B
  u16* e_bf  = (u16*)(ws + 3145728);          // 3,145,728 B
  u16* wdecT = (u16*)(ws + 2 * 3145728);      // 1,179,648 B

  prepA_kernel<<<144 + MROWS + (MROWS - ZF1), 256, 0, stream>>>(wdec, wdecT, tok, wemb,
                                                                split, nch, e_bf, out);
  udec_gemm_kernel<<<96 + (ZF1 - ZF0), 256, 0, stream>>>(e_bf, wdecT, split, nch, u, out);
  fused_kernel<<<NGEMM + ZF0, 512, 0, stream>>>(u, wemb, split, nch, out);
}